// Round 1
// 485.606 us; speedup vs baseline: 1.0444x; 1.0444x over previous
//
#include <hip/hip_runtime.h>
#include <hip/hip_bf16.h>

#define B_ 32
#define T_ 4096
#define H_ 512
#define NEGV (-1000000000.0f)
#define LOG2E 1.4426950408889634f

using bf16x8  = __attribute__((ext_vector_type(8))) __bf16;
using short8  = __attribute__((ext_vector_type(8))) short;
using f32x4   = __attribute__((ext_vector_type(4))) float;

static __device__ __forceinline__ short f2bf(float f) {
    unsigned u = __builtin_bit_cast(unsigned, f);
    unsigned r = (u + 0x7fffu + ((u >> 16) & 1u)) >> 16;
    return (short)r;
}

static __device__ __forceinline__ float tanh_fast(float x) {
    float e = __builtin_amdgcn_exp2f(x * 2.8853900817779268f); // 2*log2(e)
    return 1.0f - 2.0f * __builtin_amdgcn_rcpf(e + 1.0f);
}

static __device__ __forceinline__ f32x4 mfma16(short8 a, short8 b, f32x4 c) {
    return __builtin_amdgcn_mfma_f32_16x16x32_bf16(
        __builtin_bit_cast(bf16x8, a), __builtin_bit_cast(bf16x8, b), c, 0, 0, 0);
}

// async global->LDS, 16B per lane; lds dest = uniform base + lane*16
#define GLOAD_LDS16(g, l)                                                     \
    __builtin_amdgcn_global_load_lds(                                         \
        (const __attribute__((address_space(1))) unsigned*)(g),               \
        (__attribute__((address_space(3))) unsigned*)(l), 16, 0, 0)

// ---------------------------------------------------------------------------
// Kernel 0: Wh fp32 -> bf16, stored in EXACT MFMA fragment order.
// Chunk nc (32 Wh rows), fragment-row f = s*16+ks (0..31), lane l (0..63):
//   16B at Whp + (nc*2048 + f*64 + l)*8 shorts =
//   Wh[nc*32 + (f>>4)*16 + (l&15)][(f&15)*32 + (l>>4)*8 .. +7]
// => e_fused ds_read_b128 at (uniform + lane*16): contiguous, conflict-free.
// grid 128, block 256 (one thread per 16B fragment slot).
__global__ __launch_bounds__(256) void wh_prep(const float* __restrict__ Wh,
                                               short* __restrict__ Whp) {
    int id = blockIdx.x * 256 + threadIdx.x;   // 32768 slots
    int nc  = id >> 11;
    int rem = id & 2047;
    int f   = rem >> 6;
    int l   = rem & 63;
    int n  = nc * 32 + (f >> 4) * 16 + (l & 15);
    int k0 = (f & 15) * 32 + (l >> 4) * 8;
    const float4* src = (const float4*)(Wh + (size_t)n * H_ + k0);
    float4 f0 = src[0];
    float4 f1 = src[1];
    short8 t;
    t[0] = f2bf(f0.x); t[1] = f2bf(f0.y); t[2] = f2bf(f0.z); t[3] = f2bf(f0.w);
    t[4] = f2bf(f1.x); t[5] = f2bf(f1.y); t[6] = f2bf(f1.z); t[7] = f2bf(f1.w);
    *(short8*)(Whp + (size_t)id * 8) = t;
}

// ---------------------------------------------------------------------------
// Kernel 1: s[b,o] = sum_k dec[b,k] * Ws[o,k]    (tiny)
__global__ __launch_bounds__(256) void s_kernel(const float* __restrict__ dec,
                                                const float* __restrict__ Ws,
                                                float* __restrict__ s_out) {
    __shared__ float dec_l[H_];
    int b = blockIdx.y;
    int tid = threadIdx.x;
    dec_l[tid]       = dec[b * H_ + tid];
    dec_l[tid + 256] = dec[b * H_ + tid + 256];
    __syncthreads();
    int o = blockIdx.x * 256 + tid;
    const float4* w = (const float4*)(Ws + (size_t)o * H_);
    float acc = 0.f;
#pragma unroll 8
    for (int k = 0; k < H_ / 4; ++k) {
        float4 wv = w[k];
        acc += wv.x * dec_l[4 * k] + wv.y * dec_l[4 * k + 1] +
               wv.z * dec_l[4 * k + 2] + wv.w * dec_l[4 * k + 3];
    }
    s_out[b * H_ + o] = acc;
}

// ---------------------------------------------------------------------------
// Kernel 2 (FUSED): per 128-row block:
//   e[t] = v . tanh(enc[t,:] @ Wh^T + s[b,:])  (masked)
//   local softmax partial: m_loc, l_loc, p_t = exp(e_t - m_loc)
//   pctx[h] = sum_t p_t * enc[t,h]   (f32 re-read, L2/L3-hot)
// Writes (pctx[512], m_loc, l_loc) per block; combine_kernel merges.
// grid (B*T/128), block 256 (4 waves x 32 rows).
__global__ __launch_bounds__(256, 2) void e_fused(const float* __restrict__ enc,
                                                  const int* __restrict__ mask,
                                                  const short* __restrict__ Whp,
                                                  const float* __restrict__ s_in,
                                                  const float* __restrict__ v,
                                                  float* __restrict__ pctx,
                                                  float* __restrict__ ml) {
    __shared__ short lds_b[2][32 * 512];   // 2 x 32 KiB, fragment-ordered
    __shared__ float s_l[H_];
    __shared__ float v_l[H_];
    __shared__ float e_l[128];

    const int tid  = threadIdx.x;
    const int wave = tid >> 6;
    const int lane = tid & 63;
    const int q    = lane >> 4;   // quad 0..3
    const int lq   = lane & 15;

    const int row0 = blockIdx.x * 128;
    const int b    = row0 >> 12;   // / T_

    for (int i = tid; i < H_; i += 256) {
        s_l[i] = s_in[b * H_ + i];
        v_l[i] = v[i];
    }

    // A rows (32 per wave x 512 K) as bf16 fragments in registers.
    short8 afrag[2][16];
#pragma unroll
    for (int g = 0; g < 2; ++g) {
        int m = row0 + wave * 32 + g * 16 + lq;
        const float* ap = enc + (size_t)m * H_ + q * 8;
#pragma unroll
        for (int ks = 0; ks < 16; ++ks) {
            float4 f0 = *(const float4*)(ap + ks * 32);
            float4 f1 = *(const float4*)(ap + ks * 32 + 4);
            short8 t;
            t[0] = f2bf(f0.x); t[1] = f2bf(f0.y); t[2] = f2bf(f0.z); t[3] = f2bf(f0.w);
            t[4] = f2bf(f1.x); t[5] = f2bf(f1.y); t[6] = f2bf(f1.z); t[7] = f2bf(f1.w);
            afrag[g][ks] = t;
        }
    }

    // Prefetch chunk 0 (32 KiB): per wave 8 x 1KiB global_load_lds.
    {
        const char* gsrc = (const char*)Whp;
#pragma unroll
        for (int j = 0; j < 8; ++j) {
            int off = wave * 8192 + j * 1024;
            GLOAD_LDS16(gsrc + off + lane * 16, (char*)lds_b[0] + off);
        }
    }

    float e_acc[2][4] = {};
    __syncthreads();   // chunk 0 + s_l/v_l ready

    for (int nt = 0; nt < 16; ++nt) {
        if (nt < 15) {
            const char* gsrc = (const char*)Whp + (nt + 1) * 32768;
            short* dst = lds_b[(nt + 1) & 1];
#pragma unroll
            for (int j = 0; j < 8; ++j) {
                int off = wave * 8192 + j * 1024;
                GLOAD_LDS16(gsrc + off + lane * 16, (char*)dst + off);
            }
        }
        const short* cur = lds_b[nt & 1];
#pragma unroll
        for (int s = 0; s < 2; ++s) {
            // fragment-ordered: base + lane*16B, ks walks by immediate 1 KiB
            const short* fp = cur + s * 8192 + lane * 8;
            f32x4 acc0 = {0.f, 0.f, 0.f, 0.f};
            f32x4 acc1 = {0.f, 0.f, 0.f, 0.f};
#pragma unroll
            for (int ks = 0; ks < 16; ++ks) {
                short8 bf = *(const short8*)(fp + ks * 512);
                acc0 = mfma16(afrag[0][ks], bf, acc0);
                acc1 = mfma16(afrag[1][ks], bf, acc1);
            }
            int n = nt * 32 + s * 16 + lq;
            float sv = s_l[n];
            float vv = v_l[n];
#pragma unroll
            for (int r = 0; r < 4; ++r) {
                e_acc[0][r] += tanh_fast(acc0[r] + sv) * vv;
                e_acc[1][r] += tanh_fast(acc1[r] + sv) * vv;
            }
        }
        __syncthreads();   // all waves done with cur; prefetch of next complete
    }

    // e-reduction over 16 n-lanes -> masked e into LDS.
#pragma unroll
    for (int g = 0; g < 2; ++g)
#pragma unroll
        for (int r = 0; r < 4; ++r) {
            float t = e_acc[g][r];
            t += __shfl_xor(t, 1, 16);
            t += __shfl_xor(t, 2, 16);
            t += __shfl_xor(t, 4, 16);
            t += __shfl_xor(t, 8, 16);
            if (lq == 0) {
                int mr = wave * 32 + g * 16 + q * 4 + r;
                e_l[mr] = mask[row0 + mr] ? t : NEGV;
            }
        }
    __syncthreads();

    // Local softmax partial (wave 0): m_loc, p_t, l_loc.
    if (wave == 0) {
        float x0 = e_l[lane];
        float x1 = e_l[lane + 64];
        float m = fmaxf(x0, x1);
#pragma unroll
        for (int off = 32; off > 0; off >>= 1)
            m = fmaxf(m, __shfl_xor(m, off, 64));
        float p0 = __builtin_amdgcn_exp2f((x0 - m) * LOG2E);
        float p1 = __builtin_amdgcn_exp2f((x1 - m) * LOG2E);
        float sm = p0 + p1;
#pragma unroll
        for (int off = 32; off > 0; off >>= 1)
            sm += __shfl_xor(sm, off, 64);
        e_l[lane]      = p0;
        e_l[lane + 64] = p1;
        if (lane == 0) {
            ml[blockIdx.x * 2]     = m;
            ml[blockIdx.x * 2 + 1] = sm;
        }
    }
    __syncthreads();

    // Partial context: each thread owns one float2 of H; enc tile is L2-hot.
    const float2* ep = (const float2*)(enc + (size_t)row0 * H_) + tid;
    float2 acc = {0.f, 0.f};
#pragma unroll 8
    for (int t = 0; t < 128; ++t) {
        float w = e_l[t];                 // LDS broadcast
        float2 v2 = ep[(size_t)t * 256];
        acc.x += w * v2.x;
        acc.y += w * v2.y;
    }
    ((float2*)(pctx + (size_t)blockIdx.x * 512))[tid] = acc;
}

// ---------------------------------------------------------------------------
// Kernel 3: merge 32 block-partials per batch:
//   M = max_j m_j ; w_j = exp(m_j - M)
//   ctx[h] = sum_j w_j*pctx_j[h] / sum_j w_j*l_j
// grid (B), block 256.
__global__ __launch_bounds__(256) void combine_kernel(const float* __restrict__ pctx,
                                                      const float* __restrict__ ml,
                                                      float* __restrict__ out) {
    int b = blockIdx.x, tid = threadIdx.x;
    const float* mlb = ml + b * 64;   // 32 (m,l) pairs
    float M = -3.4e38f;
#pragma unroll
    for (int j = 0; j < 32; ++j) M = fmaxf(M, mlb[2 * j]);
    const float2* pc = (const float2*)(pctx + (size_t)b * 32 * 512) + tid;
    float denom = 0.f;
    float2 acc = {0.f, 0.f};
#pragma unroll
    for (int j = 0; j < 32; ++j) {
        float w = __builtin_amdgcn_exp2f((mlb[2 * j] - M) * LOG2E);
        denom += w * mlb[2 * j + 1];
        float2 p2 = pc[j * 256];
        acc.x += w * p2.x;
        acc.y += w * p2.y;
    }
    float inv = 1.0f / denom;
    float2 o;
    o.x = acc.x * inv;
    o.y = acc.y * inv;
    ((float2*)(out + b * H_))[tid] = o;
}

// ---------------------------------------------------------------------------
extern "C" void kernel_launch(void* const* d_in, const int* in_sizes, int n_in,
                              void* d_out, int out_size, void* d_ws, size_t ws_size,
                              hipStream_t stream) {
    (void)in_sizes; (void)n_in; (void)ws_size; (void)out_size;
    const float* enc  = (const float*)d_in[0];
    const int*   mask = (const int*)d_in[1];
    const float* dec  = (const float*)d_in[2];
    const float* Wh   = (const float*)d_in[3];
    const float* Ws   = (const float*)d_in[4];
    const float* v    = (const float*)d_in[5];
    float* out = (float*)d_out;

    short* whp_buf = (short*)d_ws;                       // 512 KiB
    float* s_buf   = (float*)(whp_buf + 512 * 512);      // 64 KiB
    float* pctx    = s_buf + B_ * H_;                    // 2 MiB (1024 x 512)
    float* ml      = pctx + 1024 * 512;                  // 8 KiB

    wh_prep<<<dim3(128), 256, 0, stream>>>(Wh, whp_buf);
    s_kernel<<<dim3(2, B_), 256, 0, stream>>>(dec, Ws, s_buf);
    e_fused<<<dim3(B_ * T_ / 128), 256, 0, stream>>>(enc, mask, whp_buf, s_buf, v,
                                                     pctx, ml);
    combine_kernel<<<dim3(B_), 256, 0, stream>>>(pctx, ml, out);
}